// Round 15
// baseline (91.680 us; speedup 1.0000x reference)
//
#include <hip/hip_runtime.h>
#include <cstddef>

#define NCAPS  10
#define BATCH  256
#define NROUTE 1152
#define CIN    8
#define COUT   16
#define PLANE  (NROUTE * 8)             // u32 (bf16x2) per (c,b) prior plane
#define XPLANE (NROUTE * CIN)           // floats per x b-plane = 9216
#define LOG2E  1.4426950408889634f
#define PRIORS_BYTES ((size_t)NCAPS * BATCH * NROUTE * 8 * 4)   // 94,371,840

// ---------- shared helpers (validated rounds 5-14) ----------
__device__ __forceinline__ unsigned swzu(unsigned unit) { return unit ^ ((unit >> 3) & 3u); }

__device__ __forceinline__ unsigned pack_bf16(float a, float b) {
    unsigned ua = __float_as_uint(a); ua += 0x7fffu + ((ua >> 16) & 1u);
    unsigned ub = __float_as_uint(b); ub += 0x7fffu + ((ub >> 16) & 1u);
    return (ua >> 16) | (ub & 0xffff0000u);
}
__device__ __forceinline__ float blo(unsigned u) { return __uint_as_float(u << 16); }
__device__ __forceinline__ float bhi(unsigned u) { return __uint_as_float(u & 0xffff0000u); }

__device__ __forceinline__ float wave_sum(float v) {
    v += __shfl_xor(v, 1);  v += __shfl_xor(v, 2);  v += __shfl_xor(v, 4);
    v += __shfl_xor(v, 8);  v += __shfl_xor(v, 16); v += __shfl_xor(v, 32);
    return v;
}

// Component-splitting butterfly: reduces s[0..15] over 64 lanes. Lane L (L<16)
// ends with the wave total of comp(L)=((L&1)<<3)|((L&2)<<1)|((L&4)>>1)|((L&8)>>3).
__device__ __forceinline__ float wave_sum16(float* s, int lane) {
#pragma unroll
    for (int j = 0; j < 8; ++j) {
        float snd = (lane & 1) ? s[j] : s[j + 8];
        float r = __shfl_xor(snd, 1);
        s[j] = ((lane & 1) ? s[j + 8] : s[j]) + r;
    }
#pragma unroll
    for (int j = 0; j < 4; ++j) {
        float snd = (lane & 2) ? s[j] : s[j + 4];
        float r = __shfl_xor(snd, 2);
        s[j] = ((lane & 2) ? s[j + 4] : s[j]) + r;
    }
#pragma unroll
    for (int j = 0; j < 2; ++j) {
        float snd = (lane & 4) ? s[j] : s[j + 2];
        float r = __shfl_xor(snd, 4);
        s[j] = ((lane & 4) ? s[j + 2] : s[j]) + r;
    }
    {
        float snd = (lane & 8) ? s[0] : s[1];
        float r = __shfl_xor(snd, 8);
        s[0] = ((lane & 8) ? s[1] : s[0]) + r;
    }
    s[0] += __shfl_xor(s[0], 16);
    s[0] += __shfl_xor(s[0], 32);
    return s[0];
}

union U4 { uint4 v; unsigned u[4]; };
union U2 { uint2 v; unsigned u[2]; };

// ======================= SPLIT PATH: kernel A (priors) =======================
// Quad unit (R12-proven shape, NB=4): route r=u>>2, out-quad j4=u&3.
// No LDS, no barrier: stores priors bf16x2 to ws, coalesced (lane->8B consec).
#define TA  512
#define NBA 4
#define NBLKA (NCAPS * (BATCH / NBA))    // 640

__global__ __launch_bounds__(TA) void caps_priors(const float* __restrict__ x,
                                                  const float* __restrict__ W,
                                                  unsigned* __restrict__ priors) {
    const int tid = threadIdx.x;
    int g    = blockIdx.x;
    int widx = (g & 7) * (NBLKA / 8) + (g >> 3);   // bijective, 640 % 8 == 0
    int c    = widx >> 6;                           // / (BATCH/NBA = 64)
    int b0   = (widx & 63) * NBA;

    const float* Wc = W + (size_t)c * (NROUTE * CIN * COUT);
    const float* xb = x + (size_t)b0 * XPLANE;

#pragma unroll 1
    for (int pass = 0; pass < (NROUTE * 4) / TA; ++pass) {   // 9 exact passes
        const int u  = pass * TA + tid;
        const int r  = u >> 2;
        const int j4 = u & 3;
        float xs[NBA][CIN];
#pragma unroll
        for (int b = 0; b < NBA; ++b) {
            const float4* xq = (const float4*)(xb + (size_t)b * XPLANE + r * CIN);
            float4 xa = xq[0], xv = xq[1];      // 4-lane broadcast
            xs[b][0] = xa.x; xs[b][1] = xa.y; xs[b][2] = xa.z; xs[b][3] = xa.w;
            xs[b][4] = xv.x; xs[b][5] = xv.y; xs[b][6] = xv.z; xs[b][7] = xv.w;
        }
        float4 acc[NBA];
#pragma unroll
        for (int b = 0; b < NBA; ++b) acc[b] = make_float4(0.f, 0.f, 0.f, 0.f);
        const float* wq = Wc + (size_t)r * (CIN * COUT) + j4 * 4;
#pragma unroll
        for (int i = 0; i < CIN; ++i) {
            float4 w = *(const float4*)(wq + i * COUT);
#pragma unroll
            for (int b = 0; b < NBA; ++b) {
                acc[b].x = fmaf(xs[b][i], w.x, acc[b].x);
                acc[b].y = fmaf(xs[b][i], w.y, acc[b].y);
                acc[b].z = fmaf(xs[b][i], w.z, acc[b].z);
                acc[b].w = fmaf(xs[b][i], w.w, acc[b].w);
            }
        }
#pragma unroll
        for (int b = 0; b < NBA; ++b) {
            U2 q;
            q.u[0] = pack_bf16(acc[b].x, acc[b].y);
            q.u[1] = pack_bf16(acc[b].z, acc[b].w);
            const size_t idx = ((size_t)(c * BATCH + b0 + b) * NROUTE + r) * 8 + j4 * 2;
            *(uint2*)&priors[idx] = q.v;       // lane->consecutive 8B: coalesced
        }
    }
}

// ======================= SPLIT PATH: kernel B (routing) ======================
// One block per (c,b); T=384; 1152 = 384*3 routes/thread in REGISTERS (24 VGPR).
// LDS = sred only (~1KB). 1 barrier/iter (parity dbuf) + redundant finish (R14).
#define TB 384
#define NWB (TB / 64)

__global__ __launch_bounds__(TB) void caps_route(const unsigned* __restrict__ priors,
                                                 float* __restrict__ out) {
    __shared__ float sred[2][NWB][20];

    const int tid  = threadIdx.x;
    const int lane = tid & 63;
    const int wv   = tid >> 6;
    const int g    = blockIdx.x;
    const int c    = g >> 8;
    const int b    = g & 255;
    const int comp = ((lane & 1) << 3) | ((lane & 2) << 1) | ((lane & 4) >> 1) | ((lane & 8) >> 3);

    const unsigned* pp = priors + (size_t)(c * BATCH + b) * PLANE;

    // load 3 routes (t, t+384, t+768) once: 6 coalesced uint4
    U4 qa0, qb0, qa1, qb1, qa2, qb2;
    {
        const unsigned* p0 = pp + (size_t)tid * 8;
        const unsigned* p1 = pp + (size_t)(tid + 384) * 8;
        const unsigned* p2 = pp + (size_t)(tid + 768) * 8;
        qa0.v = *(const uint4*)p0;  qb0.v = *(const uint4*)(p0 + 4);
        qa1.v = *(const uint4*)p1;  qb1.v = *(const uint4*)(p1 + 4);
        qa2.v = *(const uint4*)p2;  qb2.v = *(const uint4*)(p2 + 4);
    }

    float V[COUT];
#pragma unroll
    for (int o = 0; o < COUT; ++o) V[o] = 0.f;

#pragma unroll 1
    for (int it = 0; it < 3; ++it) {
        float s16[COUT];
        float se = 0.f;
#pragma unroll
        for (int o = 0; o < COUT; ++o) s16[o] = 0.f;

        // 3 route bodies (independent -> ILP); V pre-scaled by log2e -> exp2f
#pragma unroll
        for (int k = 0; k < 3; ++k) {
            const U4& qa = (k == 0) ? qa0 : (k == 1) ? qa1 : qa2;
            const U4& qb = (k == 0) ? qb0 : (k == 1) ? qb1 : qb2;
            float e;
            if (it > 0) {
                float d0 = 0.f, d1 = 0.f;
#pragma unroll
                for (int q = 0; q < 4; ++q) {
                    d0 = fmaf(blo(qa.u[q]), V[2 * q],     d0);
                    d1 = fmaf(bhi(qa.u[q]), V[2 * q + 1], d1);
                    d0 = fmaf(blo(qb.u[q]), V[8 + 2 * q], d0);
                    d1 = fmaf(bhi(qb.u[q]), V[9 + 2 * q], d1);
                }
                e = exp2f(d0 + d1);
            } else {
                e = 1.f;               // iter 0: softmax of zeros
            }
            se += e;
#pragma unroll
            for (int q = 0; q < 4; ++q) {
                s16[2 * q]     = fmaf(e, blo(qa.u[q]), s16[2 * q]);
                s16[2 * q + 1] = fmaf(e, bhi(qa.u[q]), s16[2 * q + 1]);
                s16[8 + 2 * q] = fmaf(e, blo(qb.u[q]), s16[8 + 2 * q]);
                s16[9 + 2 * q] = fmaf(e, bhi(qb.u[q]), s16[9 + 2 * q]);
            }
        }

        const float sv  = wave_sum16(s16, lane);
        const float sev = wave_sum(se);
        float (*sb)[20] = sred[it & 1];     // parity buffer: no WAR across iters
        if (lane < 16) sb[wv][comp] = sv;
        if (lane == 0) sb[wv][16]   = sev;
        __syncthreads();                     // the ONLY barrier per iteration

        // redundant finish (R14-validated): every thread reduces all 6 rows
        float Ssum[COUT];
        float SE = 0.f;
#pragma unroll
        for (int o = 0; o < COUT; ++o) Ssum[o] = 0.f;
#pragma unroll
        for (int w = 0; w < NWB; ++w) {
            const float* rp = &sb[w][0];
            float4 a0 = *(const float4*)&rp[0];
            float4 a1 = *(const float4*)&rp[4];
            float4 a2 = *(const float4*)&rp[8];
            float4 a3 = *(const float4*)&rp[12];
            Ssum[0]  += a0.x; Ssum[1]  += a0.y; Ssum[2]  += a0.z; Ssum[3]  += a0.w;
            Ssum[4]  += a1.x; Ssum[5]  += a1.y; Ssum[6]  += a1.z; Ssum[7]  += a1.w;
            Ssum[8]  += a2.x; Ssum[9]  += a2.y; Ssum[10] += a2.z; Ssum[11] += a2.w;
            Ssum[12] += a3.x; Ssum[13] += a3.y; Ssum[14] += a3.z; Ssum[15] += a3.w;
            SE += rp[16];
        }
        const float inv = 1.f / SE;
        float q2 = 0.f;
#pragma unroll
        for (int o = 0; o < COUT; ++o) q2 = fmaf(Ssum[o], Ssum[o], q2);
        const float pq = q2 * inv * inv;
        const float scale = pq / ((1.f + pq) * sqrtf(pq));

        if (it < 2) {
            const float factor = inv * scale * LOG2E;
#pragma unroll
            for (int o = 0; o < COUT; ++o) V[o] = fmaf(Ssum[o], factor, V[o]);
        } else {
            const float factor = inv * scale;
            float* op = out + (size_t)(c * BATCH + b) * COUT;
#pragma unroll
            for (int o = 0; o < COUT; ++o) {      // static index, exec-masked stores
                if (tid == o) op[o] = Ssum[o] * factor;
            }
        }
    }
}

// ===================== FALLBACK: fused single kernel (R7, 73.4us) ============
#define TF      512
#define NBF     2
#define NWAVEF  (TF / 64)
#define NBLKF   (NCAPS * (BATCH / NBF))   // 1280

__global__ __launch_bounds__(TF) void caps_fused(const float* __restrict__ x,
                                                 const float* __restrict__ W,
                                                 float* __restrict__ out) {
    __shared__ unsigned prLDS[NBF * PLANE];
    __shared__ float sred[NWAVEF][20];
    __shared__ __align__(16) float VLDS[NBF][COUT];

    const int tid  = threadIdx.x;
    const int lane = tid & 63;
    const int wv   = tid >> 6;

    int g    = blockIdx.x;
    int widx = (g & 7) * (NBLKF / 8) + (g >> 3);
    int c    = widx >> 7;
    int b0   = (widx & 127) * NBF;

    const float* Wc = W + (size_t)c * (NROUTE * CIN * COUT);
    const float* xb = x + (size_t)b0 * XPLANE;

#pragma unroll 2
    for (int pass = 0; pass < (NROUTE * 8) / TF; ++pass) {
        const int r = pass * (TF / 8) + (tid >> 3);
        const int j = tid & 7;
        float xs[NBF][CIN];
#pragma unroll
        for (int b = 0; b < NBF; ++b) {
            const float4* xq = (const float4*)(xb + (size_t)b * XPLANE + r * CIN);
            float4 xa = xq[0], xv = xq[1];
            xs[b][0] = xa.x; xs[b][1] = xa.y; xs[b][2] = xa.z; xs[b][3] = xa.w;
            xs[b][4] = xv.x; xs[b][5] = xv.y; xs[b][6] = xv.z; xs[b][7] = xv.w;
        }
        float2 acc[NBF];
#pragma unroll
        for (int b = 0; b < NBF; ++b) { acc[b].x = 0.f; acc[b].y = 0.f; }
        const float* wq = Wc + (size_t)r * (CIN * COUT) + j * 2;
#pragma unroll
        for (int i = 0; i < CIN; ++i) {
            float2 w = *(const float2*)(wq + i * COUT);
#pragma unroll
            for (int b = 0; b < NBF; ++b) {
                acc[b].x = fmaf(xs[b][i], w.x, acc[b].x);
                acc[b].y = fmaf(xs[b][i], w.y, acc[b].y);
            }
        }
        const unsigned base = swzu(2u * (unsigned)r + (unsigned)(j >> 2)) * 4u + (unsigned)(j & 3);
#pragma unroll
        for (int b = 0; b < NBF; ++b)
            prLDS[b * PLANE + base] = pack_bf16(acc[b].x, acc[b].y);
    }
    __syncthreads();

    const int bb = tid >> 8;
    const int tl = tid & 255;
    const int h  = tl & 1;
    const int r2 = 1024 + (tl >> 1);
    const int comp = ((lane & 1) << 3) | ((lane & 2) << 1) | ((lane & 4) >> 1) | ((lane & 8) >> 3);

#pragma unroll 1
    for (int it = 0; it < 3; ++it) {
        float s16[COUT];
        float se = 0.f;
#pragma unroll
        for (int o = 0; o < COUT; ++o) s16[o] = 0.f;

#pragma unroll 2
        for (int k = 0; k < 4; ++k) {
            const int r = (k << 8) + tl;
            const unsigned d0 = bb * PLANE + swzu(2u * (unsigned)r) * 4u;
            const unsigned d1 = bb * PLANE + swzu(2u * (unsigned)r + 1u) * 4u;
            U4 qa, qb;
            qa.v = *(const uint4*)&prLDS[d0];
            qb.v = *(const uint4*)&prLDS[d1];
            float p[COUT];
#pragma unroll
            for (int q = 0; q < 4; ++q) {
                p[2 * q]     = blo(qa.u[q]);  p[2 * q + 1] = bhi(qa.u[q]);
                p[8 + 2 * q] = blo(qb.u[q]);  p[9 + 2 * q] = bhi(qb.u[q]);
            }
            float e;
            if (it > 0) {
                float d = 0.f;
#pragma unroll
                for (int q = 0; q < 4; ++q) {
                    float4 v4 = *(const float4*)&VLDS[bb][4 * q];
                    d = fmaf(p[4 * q + 0], v4.x, d);
                    d = fmaf(p[4 * q + 1], v4.y, d);
                    d = fmaf(p[4 * q + 2], v4.z, d);
                    d = fmaf(p[4 * q + 3], v4.w, d);
                }
                e = __expf(d);
            } else {
                e = 1.f;
            }
            se += e;
#pragma unroll
            for (int o = 0; o < COUT; ++o) s16[o] = fmaf(e, p[o], s16[o]);
        }
        {
            const unsigned dw = bb * PLANE + swzu(2u * (unsigned)r2 + (unsigned)h) * 4u;
            U4 q;
            q.v = *(const uint4*)&prLDS[dw];
            float pl[8];
#pragma unroll
            for (int u = 0; u < 4; ++u) { pl[2 * u] = blo(q.u[u]); pl[2 * u + 1] = bhi(q.u[u]); }
            float e2;
            if (it > 0) {
                float d2 = 0.f;
#pragma unroll
                for (int j = 0; j < 8; ++j) d2 = fmaf(pl[j], VLDS[bb][h * 8 + j], d2);
                d2 += __shfl_xor(d2, 1);
                e2 = __expf(d2);
            } else {
                e2 = 1.f;
            }
            se += 0.5f * e2;
#pragma unroll
            for (int j = 0; j < 8; ++j) {
                const float add = e2 * pl[j];
                s16[j]     += (h == 0) ? add : 0.f;
                s16[8 + j] += (h == 1) ? add : 0.f;
            }
        }

        const float sv  = wave_sum16(s16, lane);
        const float sev = wave_sum(se);
        if (lane < 16) sred[wv][comp] = sv;
        if (lane == 0) sred[wv][16]   = sev;
        __syncthreads();

        if (tid < NBF * COUT) {
            const int b = tid >> 4, o = tid & 15;
            float S = 0.f, SE = 0.f;
#pragma unroll
            for (int w = 0; w < 4; ++w) {
                S  += sred[b * 4 + w][o];
                SE += sred[b * 4 + w][16];
            }
            const float tt = S / SE;
            float pq = tt * tt;
            pq += __shfl_xor(pq, 1); pq += __shfl_xor(pq, 2);
            pq += __shfl_xor(pq, 4); pq += __shfl_xor(pq, 8);
            const float scale = pq / ((1.f + pq) * sqrtf(pq));
            const float val = tt * scale;
            if (it == 2) {
                out[((size_t)c * BATCH + b0 + b) * COUT + o] = val;
            } else {
                VLDS[b][o] = (it == 0) ? val : (VLDS[b][o] + val);
            }
        }
        __syncthreads();
    }
}

extern "C" void kernel_launch(void* const* d_in, const int* in_sizes, int n_in,
                              void* d_out, int out_size, void* d_ws, size_t ws_size,
                              hipStream_t stream) {
    const float* x = (const float*)d_in[0];
    const float* w = (const float*)d_in[1];
    float* out = (float*)d_out;
    if (ws_size >= PRIORS_BYTES) {
        unsigned* priors = (unsigned*)d_ws;
        hipLaunchKernelGGL(caps_priors, dim3(NBLKA), dim3(TA), 0, stream, x, w, priors);
        hipLaunchKernelGGL(caps_route, dim3(NCAPS * BATCH), dim3(TB), 0, stream, priors, out);
    } else {
        hipLaunchKernelGGL(caps_fused, dim3(NBLKF), dim3(TF), 0, stream, x, w, out);
    }
}